// Round 1
// baseline (578.389 us; speedup 1.0000x reference)
//
#include <hip/hip_runtime.h>
#include <hip/hip_bf16.h>

// Problem constants
#define B_ 4
#define T_ 2048
#define D_ 1024
#define H_ 16
#define HD_ 64
#define M_ (B_ * T_)   // 8192 rows

typedef __attribute__((ext_vector_type(8))) short   s16x8;   // 8 bf16 (4 VGPRs) MFMA A/B frag
typedef __attribute__((ext_vector_type(4))) float   f32x4;   // MFMA C/D frag
typedef __attribute__((ext_vector_type(4))) float   fvec4;   // 16B global load
typedef __attribute__((ext_vector_type(4))) unsigned short u16x4;

__device__ inline unsigned short f2bf(float f) {
    // round-to-nearest-even fp32 -> bf16
    unsigned int u = __float_as_uint(f);
    unsigned int r = (u + 0x7fffu + ((u >> 16) & 1u)) >> 16;
    return (unsigned short)r;
}

// ---------------------------------------------------------------------------
// Kernel 1: fp32 -> bf16 convert (x pre-pass)
// ---------------------------------------------------------------------------
__global__ void cvt_bf16(const float* __restrict__ in, unsigned short* __restrict__ out) {
    int i = (blockIdx.x * 256 + threadIdx.x) * 4;
    fvec4 v = *(const fvec4*)(in + i);
    u16x4 o;
    o[0] = f2bf(v[0]); o[1] = f2bf(v[1]); o[2] = f2bf(v[2]); o[3] = f2bf(v[3]);
    *(u16x4*)(out + i) = o;
}

// ---------------------------------------------------------------------------
// Kernel 2: GEMM  C[M x N] = A(bf16, MxK) @ W(fp32, NxK)^T + bias, K=N=1024
// 256 threads, 4 waves (2x2), tile 128x128, BK=32.
// EPI=0: out bf16 [B,H,T,HD] layout (QKV), value scaled by `scale`
// EPI=1: out fp32 row-major [M x N]
// ---------------------------------------------------------------------------
template <int EPI>
__global__ __launch_bounds__(256) void gemm_bt(
    const unsigned short* __restrict__ A, const float* __restrict__ W,
    const float* __restrict__ bias, void* __restrict__ out, float scale) {
    constexpr int K = 1024;
    constexpr int LDT = 40;  // padded LDS stride (bf16 elems): 80B, 16B-aligned rows
    __shared__ unsigned short As[128 * LDT];
    __shared__ unsigned short Bs[128 * LDT];

    const int tid = threadIdx.x;
    const int wave = tid >> 6, lane = tid & 63;
    const int quad = lane >> 4, l16 = lane & 15;
    const int wr = (wave >> 1) * 64, wc = (wave & 1) * 64;
    const int m0 = blockIdx.x * 128, n0 = blockIdx.y * 128;

    f32x4 acc[4][4] = {};

    for (int k0 = 0; k0 < K; k0 += 32) {
        __syncthreads();
        // stage A tile: 128x32 bf16, 16B per xfer, 512 xfers -> 2/thread
        for (int i = 0; i < 2; ++i) {
            int idx = tid + i * 256;
            int row = idx >> 2, c8 = (idx & 3) * 8;
            s16x8 v = *(const s16x8*)(A + (size_t)(m0 + row) * K + k0 + c8);
            *(s16x8*)(As + row * LDT + c8) = v;
        }
        // stage B tile: 128x32 fp32 -> bf16, float4 loads, 1024 xfers -> 4/thread
        for (int i = 0; i < 4; ++i) {
            int idx = tid + i * 256;
            int row = idx >> 3, c4 = (idx & 7) * 4;
            fvec4 v = *(const fvec4*)(W + (size_t)(n0 + row) * K + k0 + c4);
            u16x4 o;
            o[0] = f2bf(v[0]); o[1] = f2bf(v[1]); o[2] = f2bf(v[2]); o[3] = f2bf(v[3]);
            *(u16x4*)(Bs + row * LDT + c4) = o;
        }
        __syncthreads();

        s16x8 af[4], bf[4];
        for (int i = 0; i < 4; ++i)
            af[i] = *(const s16x8*)(As + (wr + i * 16 + l16) * LDT + quad * 8);
        for (int j = 0; j < 4; ++j)
            bf[j] = *(const s16x8*)(Bs + (wc + j * 16 + l16) * LDT + quad * 8);
        for (int i = 0; i < 4; ++i)
            for (int j = 0; j < 4; ++j)
                acc[i][j] = __builtin_amdgcn_mfma_f32_16x16x32_bf16(af[i], bf[j], acc[i][j], 0, 0, 0);
    }

    // epilogue: D[m = quad*4+r][n = l16] per 16x16 tile
    for (int i = 0; i < 4; ++i) {
        int mbase = m0 + wr + i * 16 + quad * 4;
        for (int j = 0; j < 4; ++j) {
            int n = n0 + wc + j * 16 + l16;
            float bi = bias[n];
            for (int r = 0; r < 4; ++r) {
                float v = (acc[i][j][r] + bi) * scale;
                int m = mbase + r;
                if (EPI == 0) {
                    int b = m >> 11, t = m & (T_ - 1);
                    int h = n >> 6, hd = n & 63;
                    ((unsigned short*)out)[(((size_t)(b * H_ + h) * T_ + t) * HD_) + hd] = f2bf(v);
                } else {
                    ((float*)out)[(size_t)m * D_ + n] = v;
                }
            }
        }
    }
}

// ---------------------------------------------------------------------------
// Kernel 3: flash attention.  Q pre-scaled by log2(e)/8 -> softmax via exp2.
// grid (T/128, B*H), 256 threads = 4 waves; wave owns 32 query rows.
// Key chunks of 64; K,V staged in LDS (V transposed); P via LDS round-trip.
// ---------------------------------------------------------------------------
__global__ __launch_bounds__(256) void attn(
    const unsigned short* __restrict__ Qb, const unsigned short* __restrict__ Kb,
    const unsigned short* __restrict__ Vb, unsigned short* __restrict__ Ob) {
    constexpr int LDT = 72;  // padded stride for 64-wide tiles
    __shared__ unsigned short Ks[64 * LDT];
    __shared__ unsigned short Vs[64 * LDT];        // transposed: [hd][key]
    __shared__ unsigned short Ps[4][32 * LDT];     // per wave: [qrow 32][key 64]

    const int tid = threadIdx.x;
    const int wave = tid >> 6, lane = tid & 63;
    const int quad = lane >> 4, l16 = lane & 15;
    const int bh = blockIdx.y;
    const int q0 = blockIdx.x * 128;
    const size_t base = (size_t)bh * T_ * HD_;
    const unsigned short* Qp = Qb + base;
    const unsigned short* Kp = Kb + base;
    const unsigned short* Vp = Vb + base;

    // Q fragments (A-operand): row = mi*16 + l16, k = ks*32 + quad*8 + j
    s16x8 qf[2][2];
    const int qrow = q0 + wave * 32;
    for (int mi = 0; mi < 2; ++mi)
        for (int ks = 0; ks < 2; ++ks)
            qf[mi][ks] = *(const s16x8*)(Qp + (size_t)(qrow + mi * 16 + l16) * HD_ + ks * 32 + quad * 8);

    f32x4 acc_o[2][4] = {};
    float mstate[2][4], lstate[2][4];
    for (int mi = 0; mi < 2; ++mi)
        for (int r = 0; r < 4; ++r) { mstate[mi][r] = -1e30f; lstate[mi][r] = 0.f; }

    for (int k0 = 0; k0 < T_; k0 += 64) {
        __syncthreads();
        // stage K chunk 64x64 (row-major), 2 x 16B per thread
        for (int i = 0; i < 2; ++i) {
            int idx = tid + i * 256;
            int row = idx >> 3, c8 = (idx & 7) * 8;
            s16x8 v = *(const s16x8*)(Kp + (size_t)(k0 + row) * HD_ + c8);
            *(s16x8*)(Ks + row * LDT + c8) = v;
        }
        // stage V chunk transposed: Vs[hd][key]
        for (int i = 0; i < 2; ++i) {
            int idx = tid + i * 256;
            int row = idx >> 3, c8 = (idx & 7) * 8;
            s16x8 v = *(const s16x8*)(Vp + (size_t)(k0 + row) * HD_ + c8);
            for (int j = 0; j < 8; ++j) Vs[(c8 + j) * LDT + row] = (unsigned short)v[j];
        }
        __syncthreads();

        // S = Q @ K^T : per wave 32q x 64k
        f32x4 acc_s[2][4] = {};
        for (int ks = 0; ks < 2; ++ks) {
            s16x8 kf[4];
            for (int nj = 0; nj < 4; ++nj)
                kf[nj] = *(const s16x8*)(Ks + (nj * 16 + l16) * LDT + ks * 32 + quad * 8);
            for (int mi = 0; mi < 2; ++mi)
                for (int nj = 0; nj < 4; ++nj)
                    acc_s[mi][nj] = __builtin_amdgcn_mfma_f32_16x16x32_bf16(qf[mi][ks], kf[nj], acc_s[mi][nj], 0, 0, 0);
        }

        // online softmax (logits already in log2 domain)
        for (int mi = 0; mi < 2; ++mi) {
            float alpha[4];
            for (int r = 0; r < 4; ++r) {
                float mx = fmaxf(fmaxf(acc_s[mi][0][r], acc_s[mi][1][r]),
                                 fmaxf(acc_s[mi][2][r], acc_s[mi][3][r]));
                for (int off = 1; off < 16; off <<= 1)
                    mx = fmaxf(mx, __shfl_xor(mx, off, 64));
                float mnew = fmaxf(mstate[mi][r], mx);
                alpha[r] = exp2f(mstate[mi][r] - mnew);
                mstate[mi][r] = mnew;
                float rs = 0.f;
                for (int nj = 0; nj < 4; ++nj) {
                    float p = exp2f(acc_s[mi][nj][r] - mnew);
                    acc_s[mi][nj][r] = p;
                    rs += p;
                }
                for (int off = 1; off < 16; off <<= 1)
                    rs += __shfl_xor(rs, off, 64);
                lstate[mi][r] = lstate[mi][r] * alpha[r] + rs;
            }
            for (int nh = 0; nh < 4; ++nh)
                for (int r = 0; r < 4; ++r)
                    acc_o[mi][nh][r] *= alpha[r];
            // P -> LDS (C-layout write)
            for (int nj = 0; nj < 4; ++nj)
                for (int r = 0; r < 4; ++r)
                    Ps[wave][(mi * 16 + quad * 4 + r) * LDT + nj * 16 + l16] = f2bf(acc_s[mi][nj][r]);
        }
        asm volatile("s_waitcnt lgkmcnt(0)" ::: "memory");  // wave-internal LDS RAW

        // O += P @ V : P as A-operand from LDS, V^T rows as B-operand
        for (int ks = 0; ks < 2; ++ks) {
            s16x8 vf[4];
            for (int nh = 0; nh < 4; ++nh)
                vf[nh] = *(const s16x8*)(Vs + (nh * 16 + l16) * LDT + ks * 32 + quad * 8);
            for (int mi = 0; mi < 2; ++mi) {
                s16x8 pf = *(const s16x8*)(Ps[wave] + (mi * 16 + l16) * LDT + ks * 32 + quad * 8);
                for (int nh = 0; nh < 4; ++nh)
                    acc_o[mi][nh] = __builtin_amdgcn_mfma_f32_16x16x32_bf16(pf, vf[nh], acc_o[mi][nh], 0, 0, 0);
            }
        }
    }

    // epilogue: Ob[b, t, h*64+hd] bf16
    const int b = bh >> 4, h = bh & 15;
    for (int mi = 0; mi < 2; ++mi) {
        for (int r = 0; r < 4; ++r) {
            int t = qrow + mi * 16 + quad * 4 + r;
            float inv = 1.f / lstate[mi][r];
            for (int nh = 0; nh < 4; ++nh) {
                float v = acc_o[mi][nh][r] * inv;
                Ob[((size_t)b * T_ + t) * D_ + h * 64 + nh * 16 + l16] = f2bf(v);
            }
        }
    }
}

// ---------------------------------------------------------------------------
extern "C" void kernel_launch(void* const* d_in, const int* in_sizes, int n_in,
                              void* d_out, int out_size, void* d_ws, size_t ws_size,
                              hipStream_t stream) {
    const float* x  = (const float*)d_in[0];
    const float* Wq = (const float*)d_in[1];
    const float* bq = (const float*)d_in[2];
    const float* Wk = (const float*)d_in[3];
    const float* bk = (const float*)d_in[4];
    const float* Wv = (const float*)d_in[5];
    const float* bv = (const float*)d_in[6];
    const float* Wo = (const float*)d_in[7];
    const float* bo = (const float*)d_in[8];
    float* out = (float*)d_out;

    // workspace layout (bf16 halves): xb | Qb | Kb | Vb | Ob, 16MB each
    const size_t SZ = (size_t)M_ * D_ * sizeof(unsigned short);  // 16 MiB
    unsigned short* xb = (unsigned short*)d_ws;
    unsigned short* Qb = (unsigned short*)((char*)d_ws + 1 * SZ);
    unsigned short* Kb = (unsigned short*)((char*)d_ws + 2 * SZ);
    unsigned short* Vb = (unsigned short*)((char*)d_ws + 3 * SZ);
    unsigned short* Ob = (unsigned short*)((char*)d_ws + 4 * SZ);

    const float qscale = 1.4426950408889634f / 8.0f;  // log2(e)/sqrt(HD)

    dim3 blk(256);
    cvt_bf16<<<dim3((M_ * D_) / (256 * 4)), blk, 0, stream>>>(x, xb);
    gemm_bt<0><<<dim3(M_ / 128, D_ / 128), blk, 0, stream>>>(xb, Wq, bq, Qb, qscale);
    gemm_bt<0><<<dim3(M_ / 128, D_ / 128), blk, 0, stream>>>(xb, Wk, bk, Kb, 1.0f);
    gemm_bt<0><<<dim3(M_ / 128, D_ / 128), blk, 0, stream>>>(xb, Wv, bv, Vb, 1.0f);
    attn<<<dim3(T_ / 128, B_ * H_), blk, 0, stream>>>(Qb, Kb, Vb, Ob);
    gemm_bt<1><<<dim3(M_ / 128, D_ / 128), blk, 0, stream>>>(Ob, Wo, bo, out, 1.0f);
}

// Round 2
// 396.466 us; speedup vs baseline: 1.4589x; 1.4589x over previous
//
#include <hip/hip_runtime.h>
#include <hip/hip_bf16.h>

// Problem constants
#define B_ 4
#define T_ 2048
#define D_ 1024
#define H_ 16
#define HD_ 64
#define M_ (B_ * T_)   // 8192 rows

typedef __attribute__((ext_vector_type(8))) short   s16x8;
typedef __attribute__((ext_vector_type(4))) short   s16x4;   // K=16 MFMA A/B frag (2 VGPRs)
typedef __attribute__((ext_vector_type(4))) float   f32x4;
typedef __attribute__((ext_vector_type(4))) float   fvec4;
typedef __attribute__((ext_vector_type(4))) unsigned short u16x4;

__device__ inline unsigned short f2bf(float f) {
    unsigned int u = __float_as_uint(f);
    return (unsigned short)((u + 0x7fffu + ((u >> 16) & 1u)) >> 16);
}

#if __has_builtin(__builtin_amdgcn_mfma_f32_16x16x16bf16_1k)
__device__ inline f32x4 mfma16(s16x4 a, s16x4 b, f32x4 c) {
    return __builtin_amdgcn_mfma_f32_16x16x16bf16_1k(a, b, c, 0, 0, 0);
}
#else
__device__ inline f32x4 mfma16(s16x4 a, s16x4 b, f32x4 c) {
    asm volatile("v_mfma_f32_16x16x16_bf16 %0, %1, %2, %0\n\ts_nop 7\n\ts_nop 7"
                 : "+v"(c) : "v"(a), "v"(b));
    return c;
}
#endif

// async global->LDS, 16B per lane; LDS dest must be wave-uniform base + lane*16
__device__ inline void gld16(const unsigned short* g, unsigned short* l) {
    __builtin_amdgcn_global_load_lds(
        (const __attribute__((address_space(1))) unsigned int*)g,
        (__attribute__((address_space(3))) unsigned int*)l, 16, 0, 0);
}

// ---------------------------------------------------------------------------
// fp32 -> bf16 convert (x and weights)
// ---------------------------------------------------------------------------
__global__ void cvt_bf16(const float* __restrict__ in, unsigned short* __restrict__ out) {
    int i = (blockIdx.x * 256 + threadIdx.x) * 4;
    fvec4 v = *(const fvec4*)(in + i);
    u16x4 o;
    o[0] = f2bf(v[0]); o[1] = f2bf(v[1]); o[2] = f2bf(v[2]); o[3] = f2bf(v[3]);
    *(u16x4*)(out + i) = o;
}

// ---------------------------------------------------------------------------
// GEMM  C[M x N] = A(bf16, MxK) @ Wb(bf16, NxK)^T + bias, K=N=1024
// m97 structure: 128x128 tile, BK=32, global_load_lds width=16, unpadded LDS.
// EPI=0: bf16 out [B,H,T,HD] * scale (Q/K)
// EPI=1: fp32 out row-major (final)
// EPI=2: bf16 out transposed [B,H,HD,T] (V^T), 8B packed stores
// ---------------------------------------------------------------------------
template <int EPI>
__global__ __launch_bounds__(256) void gemm_bt(
    const unsigned short* __restrict__ A, const unsigned short* __restrict__ Wb,
    const float* __restrict__ bias, void* __restrict__ out, float scale) {
    constexpr int K = 1024;
    __shared__ __align__(16) unsigned short As[128 * 32];
    __shared__ __align__(16) unsigned short Bs[128 * 32];

    const int tid = threadIdx.x;
    const int wave = tid >> 6, lane = tid & 63;
    const int quad = lane >> 4, l16 = lane & 15;
    const int wr = (wave >> 1) * 64, wc = (wave & 1) * 64;
    const int m0 = blockIdx.x * 128, n0 = blockIdx.y * 128;

    f32x4 acc[4][4] = {};

    for (int k0 = 0; k0 < K; k0 += 32) {
        __syncthreads();
        for (int i = 0; i < 2; ++i) {
            int idx = tid + i * 256;
            int row = idx >> 2, c8 = (idx & 3) * 8;
            gld16(A  + (size_t)(m0 + row) * K + k0 + c8, As + idx * 8);
            gld16(Wb + (size_t)(n0 + row) * K + k0 + c8, Bs + idx * 8);
        }
        __syncthreads();

        s16x8 af[4], bfr[4];
        for (int i = 0; i < 4; ++i)
            af[i] = *(const s16x8*)(As + (wr + i * 16 + l16) * 32 + quad * 8);
        for (int j = 0; j < 4; ++j)
            bfr[j] = *(const s16x8*)(Bs + (wc + j * 16 + l16) * 32 + quad * 8);
        for (int i = 0; i < 4; ++i)
            for (int j = 0; j < 4; ++j)
                acc[i][j] = __builtin_amdgcn_mfma_f32_16x16x32_bf16(af[i], bfr[j], acc[i][j], 0, 0, 0);
    }

    for (int i = 0; i < 4; ++i) {
        int mbase = m0 + wr + i * 16 + quad * 4;  // 4 consecutive m (same b, consecutive t)
        int b = mbase >> 11, t = mbase & (T_ - 1);
        for (int j = 0; j < 4; ++j) {
            int n = n0 + wc + j * 16 + l16;
            float bi = bias[n];
            int h = n >> 6, hd = n & 63;
            if (EPI == 0) {
                for (int r = 0; r < 4; ++r) {
                    float v = (acc[i][j][r] + bi) * scale;
                    ((unsigned short*)out)[(((size_t)(b * H_ + h) * T_ + t + r) * HD_) + hd] = f2bf(v);
                }
            } else if (EPI == 2) {
                u16x4 o;
                for (int r = 0; r < 4; ++r) o[r] = f2bf(acc[i][j][r] + bi);
                *(u16x4*)((unsigned short*)out + ((size_t)(b * H_ + h) * HD_ + hd) * T_ + t) = o;
            } else {
                for (int r = 0; r < 4; ++r)
                    ((float*)out)[(size_t)(mbase + r) * D_ + n] = acc[i][j][r] + bi;
            }
        }
    }
}

// ---------------------------------------------------------------------------
// Flash attention, S^T formulation with 16x16x16 MFMA.
// Block: 4 waves x 32 queries = 128 q, one (b,h). Key chunks of 64.
// S^T = K @ Q^T -> C-layout (key=quad*4+r, q=l16) == B-frag layout for PV,
// so P^T feeds the O^T = V^T @ P^T MFMA directly from registers (no LDS trip).
// V arrives pre-transposed [B,H,HD,T]; K,V^T staged in LDS (stride 72: b64
// frag reads land 2 lanes/bank = free).
// ---------------------------------------------------------------------------
__global__ __launch_bounds__(256) void attn(
    const unsigned short* __restrict__ Qb, const unsigned short* __restrict__ Kb,
    const unsigned short* __restrict__ Vt, unsigned short* __restrict__ Ob) {
    constexpr int LDK = 72;
    __shared__ __align__(16) unsigned short Ks[64 * LDK];
    __shared__ __align__(16) unsigned short Vs[64 * LDK];

    const int tid = threadIdx.x;
    const int wave = tid >> 6, lane = tid & 63;
    const int quad = lane >> 4, l16 = lane & 15;
    const int bh = blockIdx.y, b = bh >> 4, h = bh & 15;
    const int q0 = blockIdx.x * 128 + wave * 32;
    const unsigned short* Qp = Qb + (size_t)bh * T_ * HD_;
    const unsigned short* Kp = Kb + (size_t)bh * T_ * HD_;
    const unsigned short* Vp = Vt + (size_t)bh * HD_ * T_;

    // Q as B-operand: B[k=d=quad*4+j][n=q=l16]
    s16x4 qf[2][4];
    for (int qt = 0; qt < 2; ++qt)
        for (int ds = 0; ds < 4; ++ds)
            qf[qt][ds] = *(const s16x4*)(Qp + (size_t)(q0 + qt * 16 + l16) * HD_ + ds * 16 + quad * 4);

    f32x4 accO[2][4] = {};             // O^T[d=dt*16+quad*4+r][q=qt*16+l16]
    float mst[2] = {-1e30f, -1e30f};
    float lst[2] = {0.f, 0.f};

    for (int k0 = 0; k0 < T_; k0 += 64) {
        __syncthreads();
        for (int i = 0; i < 2; ++i) {
            int idx = tid + i * 256;
            int row = idx >> 3, c8 = (idx & 7) * 8;
            *(s16x8*)(Ks + row * LDK + c8) = *(const s16x8*)(Kp + (size_t)(k0 + row) * HD_ + c8);
            *(s16x8*)(Vs + row * LDK + c8) = *(const s16x8*)(Vp + (size_t)row * T_ + k0 + c8);
        }
        __syncthreads();

        // S^T[key][q]: A = K rows, B = Q
        f32x4 st[2][4] = {};
        for (int kt = 0; kt < 4; ++kt) {
            s16x4 kf[4];
            for (int ds = 0; ds < 4; ++ds)
                kf[ds] = *(const s16x4*)(Ks + (kt * 16 + l16) * LDK + ds * 16 + quad * 4);
            for (int qt = 0; qt < 2; ++qt)
                for (int ds = 0; ds < 4; ++ds)
                    st[qt][kt] = mfma16(kf[ds], qf[qt][ds], st[qt][kt]);
        }

        // online softmax per query column (q=l16); logits already log2-domain
        s16x4 pb[2][4];
        for (int qt = 0; qt < 2; ++qt) {
            float mx = st[qt][0][0];
            for (int kt = 0; kt < 4; ++kt)
                for (int r = 0; r < 4; ++r) mx = fmaxf(mx, st[qt][kt][r]);
            mx = fmaxf(mx, __shfl_xor(mx, 16, 64));
            mx = fmaxf(mx, __shfl_xor(mx, 32, 64));
            float mnew = fmaxf(mst[qt], mx);
            float al = __builtin_amdgcn_exp2f(mst[qt] - mnew);
            mst[qt] = mnew;
            float rs = 0.f;
            for (int kt = 0; kt < 4; ++kt) {
                f32x4 p;
                for (int r = 0; r < 4; ++r) { p[r] = __builtin_amdgcn_exp2f(st[qt][kt][r] - mnew); rs += p[r]; }
                s16x4 pk;
                for (int r = 0; r < 4; ++r) pk[r] = (short)f2bf(p[r]);
                pb[qt][kt] = pk;   // B-frag: k=key=quad*4+r, n=q=l16 — direct reuse
            }
            rs += __shfl_xor(rs, 16, 64);
            rs += __shfl_xor(rs, 32, 64);
            lst[qt] = lst[qt] * al + rs;
            for (int dt = 0; dt < 4; ++dt)
                for (int r = 0; r < 4; ++r) accO[qt][dt][r] *= al;
        }

        // O^T += V^T @ P^T : A = V^T rows from LDS, B = pb from registers
        for (int kk = 0; kk < 4; ++kk)
            for (int dt = 0; dt < 4; ++dt) {
                s16x4 vf = *(const s16x4*)(Vs + (dt * 16 + l16) * LDK + kk * 16 + quad * 4);
                for (int qt = 0; qt < 2; ++qt)
                    accO[qt][dt] = mfma16(vf, pb[qt][kk], accO[qt][dt]);
            }
    }

    // epilogue: Ob[b, t, h*64 + d] bf16; pack 4 consecutive d -> 8B stores
    for (int qt = 0; qt < 2; ++qt) {
        float inv = 1.f / lst[qt];
        int t = q0 + qt * 16 + l16;
        for (int dt = 0; dt < 4; ++dt) {
            u16x4 o;
            for (int r = 0; r < 4; ++r) o[r] = f2bf(accO[qt][dt][r] * inv);
            *(u16x4*)(Ob + ((size_t)b * T_ + t) * D_ + h * 64 + dt * 16 + quad * 4) = o;
        }
    }
}

// ---------------------------------------------------------------------------
extern "C" void kernel_launch(void* const* d_in, const int* in_sizes, int n_in,
                              void* d_out, int out_size, void* d_ws, size_t ws_size,
                              hipStream_t stream) {
    const float* x  = (const float*)d_in[0];
    const float* Wq = (const float*)d_in[1];
    const float* bq = (const float*)d_in[2];
    const float* Wk = (const float*)d_in[3];
    const float* bk = (const float*)d_in[4];
    const float* Wv = (const float*)d_in[5];
    const float* bv = (const float*)d_in[6];
    const float* Wo = (const float*)d_in[7];
    const float* bo = (const float*)d_in[8];
    float* out = (float*)d_out;

    // workspace: xb(16M, later aliased by Ob) | Qb | Kb | Vbt (16M each) | 4 bf16 weights (2M each) = 72MB
    const size_t SZ = (size_t)M_ * D_ * sizeof(unsigned short);   // 16 MiB
    const size_t WZ = (size_t)D_ * D_ * sizeof(unsigned short);   // 2 MiB
    unsigned short* xb  = (unsigned short*)d_ws;
    unsigned short* Qb  = (unsigned short*)((char*)d_ws + 1 * SZ);
    unsigned short* Kb  = (unsigned short*)((char*)d_ws + 2 * SZ);
    unsigned short* Vbt = (unsigned short*)((char*)d_ws + 3 * SZ);
    unsigned short* Wqb = (unsigned short*)((char*)d_ws + 4 * SZ);
    unsigned short* Wkb = (unsigned short*)((char*)d_ws + 4 * SZ + 1 * WZ);
    unsigned short* Wvb = (unsigned short*)((char*)d_ws + 4 * SZ + 2 * WZ);
    unsigned short* Wob = (unsigned short*)((char*)d_ws + 4 * SZ + 3 * WZ);
    unsigned short* Ob  = xb;  // xb dead after the V GEMM

    const float qscale = 1.4426950408889634f / 8.0f;  // log2(e)/sqrt(HD)

    dim3 blk(256);
    cvt_bf16<<<dim3((M_ * D_) / 1024), blk, 0, stream>>>(x, xb);
    cvt_bf16<<<dim3((D_ * D_) / 1024), blk, 0, stream>>>(Wq, Wqb);
    cvt_bf16<<<dim3((D_ * D_) / 1024), blk, 0, stream>>>(Wk, Wkb);
    cvt_bf16<<<dim3((D_ * D_) / 1024), blk, 0, stream>>>(Wv, Wvb);
    cvt_bf16<<<dim3((D_ * D_) / 1024), blk, 0, stream>>>(Wo, Wob);
    gemm_bt<0><<<dim3(M_ / 128, D_ / 128), blk, 0, stream>>>(xb, Wqb, bq, Qb, qscale);
    gemm_bt<0><<<dim3(M_ / 128, D_ / 128), blk, 0, stream>>>(xb, Wkb, bk, Kb, 1.0f);
    gemm_bt<2><<<dim3(M_ / 128, D_ / 128), blk, 0, stream>>>(xb, Wvb, bv, Vbt, 1.0f);
    attn<<<dim3(T_ / 128, B_ * H_), blk, 0, stream>>>(Qb, Kb, Vbt, Ob);
    gemm_bt<1><<<dim3(M_ / 128, D_ / 128), blk, 0, stream>>>(Ob, Wob, bo, out, 1.0f);
}

// Round 4
// 329.614 us; speedup vs baseline: 1.7547x; 1.2028x over previous
//
#include <hip/hip_runtime.h>
#include <hip/hip_bf16.h>

// Problem constants
#define B_ 4
#define T_ 2048
#define D_ 1024
#define H_ 16
#define HD_ 64
#define M_ (B_ * T_)   // 8192 rows

typedef __attribute__((ext_vector_type(8))) short   s16x8;
typedef __attribute__((ext_vector_type(4))) short   s16x4;
typedef __attribute__((ext_vector_type(4))) float   f32x4;
typedef __attribute__((ext_vector_type(4))) float   fvec4;
typedef __attribute__((ext_vector_type(4))) unsigned short u16x4;

union U4 { u16x4 v; unsigned int w[2]; };
union P2 { s16x4 v; unsigned int w[2]; };

__device__ inline unsigned short f2bf(float f) {
    unsigned int u = __float_as_uint(f);
    return (unsigned short)((u + 0x7fffu + ((u >> 16) & 1u)) >> 16);
}

// pack two fp32 -> one dword of 2 bf16 (RNE)
__device__ inline unsigned int pk_bf16(float a, float b) {
#if __has_builtin(__builtin_amdgcn_cvt_pk_bf16_f32)
    typedef __attribute__((ext_vector_type(2))) __bf16 bf2_t;
    bf2_t r = __builtin_amdgcn_cvt_pk_bf16_f32(a, b);
    unsigned int u;
    __builtin_memcpy(&u, &r, 4);
    return u;
#else
    return (unsigned int)f2bf(a) | ((unsigned int)f2bf(b) << 16);
#endif
}

#if __has_builtin(__builtin_amdgcn_mfma_f32_16x16x16bf16_1k)
__device__ inline f32x4 mfma16(s16x4 a, s16x4 b, f32x4 c) {
    return __builtin_amdgcn_mfma_f32_16x16x16bf16_1k(a, b, c, 0, 0, 0);
}
#else
__device__ inline f32x4 mfma16(s16x4 a, s16x4 b, f32x4 c) {
    asm volatile("v_mfma_f32_16x16x16_bf16 %0, %1, %2, %0\n\ts_nop 7\n\ts_nop 7"
                 : "+v"(c) : "v"(a), "v"(b));
    return c;
}
#endif

__device__ inline f32x4 mfma32(s16x8 a, s16x8 b, f32x4 c) {
    return __builtin_amdgcn_mfma_f32_16x16x32_bf16(a, b, c, 0, 0, 0);
}

// async global->LDS, 16B/lane; LDS dest = wave-uniform base + lane*16
__device__ inline void gld16(const unsigned short* g, unsigned short* l) {
    __builtin_amdgcn_global_load_lds(
        (const __attribute__((address_space(1))) unsigned int*)g,
        (__attribute__((address_space(3))) unsigned int*)l, 16, 0, 0);
}

// ---------------------------------------------------------------------------
// Fused fp32->bf16 convert: x (8192 blocks) + 4 weights (1024 blocks each)
// ---------------------------------------------------------------------------
__global__ void cvt_all(const float* __restrict__ x,
                        const float* __restrict__ wq, const float* __restrict__ wk,
                        const float* __restrict__ wv, const float* __restrict__ wo,
                        unsigned short* __restrict__ xb, unsigned short* __restrict__ wcat) {
    const int bid = blockIdx.x;
    const float* src; unsigned short* dst; int off;
    if (bid < 8192)       { src = x;  dst = xb;                  off = bid; }
    else if (bid < 9216)  { src = wq; dst = wcat;                off = bid - 8192; }
    else if (bid < 10240) { src = wk; dst = wcat + 1 * 1048576;  off = bid - 9216; }
    else if (bid < 11264) { src = wv; dst = wcat + 2 * 1048576;  off = bid - 10240; }
    else                  { src = wo; dst = wcat + 3 * 1048576;  off = bid - 11264; }
    int i = off * 1024 + threadIdx.x * 4;
    fvec4 v = *(const fvec4*)(src + i);
    U4 o;
    o.w[0] = pk_bf16(v[0], v[1]);
    o.w[1] = pk_bf16(v[2], v[3]);
    *(u16x4*)(dst + i) = o.v;
}

// ---------------------------------------------------------------------------
// GEMM core: 128x128 tile, BK=32, gld16 staging, double-buffered LDS,
// one barrier per K-step. acc[4][4] per wave (4 waves, 2x2).
// ---------------------------------------------------------------------------
#define GEMM_BODY(A_, W_)                                                          \
    __shared__ __align__(16) unsigned short As[2][128 * 32];                       \
    __shared__ __align__(16) unsigned short Bs[2][128 * 32];                       \
    const int tid = threadIdx.x;                                                   \
    const int wave = tid >> 6, lane = tid & 63;                                    \
    const int quad = lane >> 4, l16 = lane & 15;                                   \
    const int wr = (wave >> 1) * 64, wc = (wave & 1) * 64;                         \
    f32x4 acc[4][4] = {};                                                          \
    {                                                                              \
        for (int i = 0; i < 2; ++i) {                                              \
            int idx = tid + i * 256;                                               \
            int row = idx >> 2, c8 = (idx & 3) * 8;                                \
            gld16(A_ + (size_t)(m0 + row) * 1024 + c8, As[0] + idx * 8);           \
            gld16(W_ + (size_t)(n0 + row) * 1024 + c8, Bs[0] + idx * 8);           \
        }                                                                          \
    }                                                                              \
    for (int c = 0; c < 32; ++c) {                                                 \
        __syncthreads();                                                           \
        if (c + 1 < 32) {                                                          \
            int kn = (c + 1) * 32, nb = (c + 1) & 1;                               \
            for (int i = 0; i < 2; ++i) {                                          \
                int idx = tid + i * 256;                                           \
                int row = idx >> 2, c8 = (idx & 3) * 8;                            \
                gld16(A_ + (size_t)(m0 + row) * 1024 + kn + c8, As[nb] + idx * 8); \
                gld16(W_ + (size_t)(n0 + row) * 1024 + kn + c8, Bs[nb] + idx * 8); \
            }                                                                      \
        }                                                                          \
        const unsigned short* Ac = As[c & 1];                                      \
        const unsigned short* Bc = Bs[c & 1];                                      \
        s16x8 af[4], bfr[4];                                                       \
        for (int i = 0; i < 4; ++i)                                                \
            af[i] = *(const s16x8*)(Ac + (wr + i * 16 + l16) * 32 + quad * 8);     \
        for (int j = 0; j < 4; ++j)                                                \
            bfr[j] = *(const s16x8*)(Bc + (wc + j * 16 + l16) * 32 + quad * 8);    \
        for (int i = 0; i < 4; ++i)                                                \
            for (int j = 0; j < 4; ++j)                                            \
                acc[i][j] = mfma32(af[i], bfr[j], acc[i][j]);                      \
    }

// Fused Q/K/V projection: grid (64, 24); y>>3 selects proj, y&7 the n-tile.
__global__ __launch_bounds__(256) void gemm_qkv(
    const unsigned short* __restrict__ A, const unsigned short* __restrict__ Wcat,
    const float* __restrict__ bq, const float* __restrict__ bk, const float* __restrict__ bv,
    unsigned short* __restrict__ Qb, unsigned short* __restrict__ Kb,
    unsigned short* __restrict__ Vt, float qscale) {
    const int proj = blockIdx.y >> 3;
    const int m0 = blockIdx.x * 128, n0 = (blockIdx.y & 7) * 128;
    const unsigned short* W = Wcat + (size_t)proj * 1048576;
    const float* bias = proj == 0 ? bq : (proj == 1 ? bk : bv);

    GEMM_BODY(A, W)

    const float scale = (proj == 0) ? qscale : 1.0f;
    unsigned short* outp = (proj == 0) ? Qb : (proj == 1 ? Kb : Vt);
    for (int i = 0; i < 4; ++i) {
        int mbase = m0 + wr + i * 16 + quad * 4;   // 4 consecutive t, same b
        int b = mbase >> 11, t = mbase & (T_ - 1);
        for (int j = 0; j < 4; ++j) {
            int n = n0 + wc + j * 16 + l16;
            float bi = bias[n];
            int h = n >> 6, hd = n & 63;
            if (proj == 2) {   // V^T layout [B,H,HD,T], 8B packed stores
                U4 o;
                o.w[0] = pk_bf16(acc[i][j][0] + bi, acc[i][j][1] + bi);
                o.w[1] = pk_bf16(acc[i][j][2] + bi, acc[i][j][3] + bi);
                *(u16x4*)(outp + ((size_t)(b * H_ + h) * HD_ + hd) * T_ + t) = o.v;
            } else {           // [B,H,T,HD]
                for (int r = 0; r < 4; ++r) {
                    float v = (acc[i][j][r] + bi) * scale;
                    outp[(((size_t)(b * H_ + h) * T_ + t + r) * HD_) + hd] = f2bf(v);
                }
            }
        }
    }
}

// Output projection: fp32 row-major out.
__global__ __launch_bounds__(256) void gemm_o(
    const unsigned short* __restrict__ A, const unsigned short* __restrict__ W,
    const float* __restrict__ bias, float* __restrict__ out) {
    const int m0 = blockIdx.x * 128, n0 = blockIdx.y * 128;

    GEMM_BODY(A, W)

    for (int i = 0; i < 4; ++i) {
        int mbase = m0 + wr + i * 16 + quad * 4;
        for (int j = 0; j < 4; ++j) {
            int n = n0 + wc + j * 16 + l16;
            float bi = bias[n];
            for (int r = 0; r < 4; ++r)
                out[(size_t)(mbase + r) * D_ + n] = acc[i][j][r] + bi;
        }
    }
}

// ---------------------------------------------------------------------------
// Flash attention, S^T formulation.
// S^T = K@Q^T via 16x16x32 MFMA (C-layout [key=quad*4+r][q=l16]);
// P^T is directly the x16 B-frag for O^T = V^T@P^T (no LDS round-trip).
// Double-buffered K/V chunks (64 keys), ONE barrier per chunk, register
// prefetch overlaps global latency with compute. Per-lane partial l;
// accO rescale wave-skipped when no new max.
// ---------------------------------------------------------------------------
__global__ __launch_bounds__(256) void attn(
    const unsigned short* __restrict__ Qb, const unsigned short* __restrict__ Kb,
    const unsigned short* __restrict__ Vt, unsigned short* __restrict__ Ob) {
    constexpr int LDK = 72;
    constexpr int KBUF = 64 * LDK;
    __shared__ __align__(16) unsigned short Ks[2 * KBUF];
    __shared__ __align__(16) unsigned short Vs[2 * KBUF];

    const int tid = threadIdx.x;
    const int wave = tid >> 6, lane = tid & 63;
    const int quad = lane >> 4, l16 = lane & 15;
    const int bh = blockIdx.y, b = bh >> 4, h = bh & 15;
    const int q0 = blockIdx.x * 128 + wave * 32;
    const unsigned short* Qp = Qb + (size_t)bh * T_ * HD_;
    const unsigned short* Kp = Kb + (size_t)bh * T_ * HD_;
    const unsigned short* Vp = Vt + (size_t)bh * HD_ * T_;

    // Q as x32 B-operand: B[k=d=ds*32+quad*8+j][n=q=l16]
    s16x8 qf[2][2];
    for (int qt = 0; qt < 2; ++qt)
        for (int ds = 0; ds < 2; ++ds)
            qf[qt][ds] = *(const s16x8*)(Qp + (size_t)(q0 + qt * 16 + l16) * HD_ + ds * 32 + quad * 8);

    f32x4 accO[2][4] = {};             // O^T[d=dt*16+quad*4+r][q=qt*16+l16]
    float mst[2] = {-1e30f, -1e30f};
    float lst[2] = {0.f, 0.f};         // per-lane partial (this lane's keys)

    const int srow = tid >> 3, sc8 = (tid & 7) * 8;        // staging coords (i=0)
    const int srow1 = (tid + 256) >> 3;                    // i=1

    // prologue: stage chunk 0 into buf 0
    {
        *(s16x8*)(Ks + srow  * LDK + sc8) = *(const s16x8*)(Kp + (size_t)srow  * HD_ + sc8);
        *(s16x8*)(Ks + srow1 * LDK + sc8) = *(const s16x8*)(Kp + (size_t)srow1 * HD_ + sc8);
        *(s16x8*)(Vs + srow  * LDK + sc8) = *(const s16x8*)(Vp + (size_t)srow  * T_ + sc8);
        *(s16x8*)(Vs + srow1 * LDK + sc8) = *(const s16x8*)(Vp + (size_t)srow1 * T_ + sc8);
    }

    int cur = 0;
    for (int c = 0; c < T_ / 64; ++c) {
        __syncthreads();   // buf[cur] ready; reads of buf[cur^1] (iter c-1) done

        // prefetch chunk c+1 into registers (latency overlaps compute below)
        s16x8 kreg0, kreg1, vreg0, vreg1;
        const bool pf = (c + 1 < T_ / 64);
        if (pf) {
            int kn = (c + 1) * 64;
            kreg0 = *(const s16x8*)(Kp + (size_t)(kn + srow)  * HD_ + sc8);
            kreg1 = *(const s16x8*)(Kp + (size_t)(kn + srow1) * HD_ + sc8);
            vreg0 = *(const s16x8*)(Vp + (size_t)srow  * T_ + kn + sc8);
            vreg1 = *(const s16x8*)(Vp + (size_t)srow1 * T_ + kn + sc8);
        }

        const unsigned short* Kc = Ks + cur * KBUF;
        const unsigned short* Vc = Vs + cur * KBUF;

        // S^T[key][q] via x32: A = K rows (b128 LDS), B = Q (regs)
        f32x4 st[2][4] = {};
        for (int kt = 0; kt < 4; ++kt) {
            s16x8 kf0 = *(const s16x8*)(Kc + (kt * 16 + l16) * LDK + quad * 8);
            s16x8 kf1 = *(const s16x8*)(Kc + (kt * 16 + l16) * LDK + 32 + quad * 8);
            for (int qt = 0; qt < 2; ++qt) {
                st[qt][kt] = mfma32(kf0, qf[qt][0], st[qt][kt]);
                st[qt][kt] = mfma32(kf1, qf[qt][1], st[qt][kt]);
            }
        }

        // online softmax per q column (logits in log2 domain)
        s16x4 pb[2][4];
        for (int qt = 0; qt < 2; ++qt) {
            float mx = fmaxf(fmaxf(st[qt][0][0], st[qt][0][1]), fmaxf(st[qt][0][2], st[qt][0][3]));
            for (int kt = 1; kt < 4; ++kt)
                for (int r = 0; r < 4; ++r) mx = fmaxf(mx, st[qt][kt][r]);
            mx = fmaxf(mx, __shfl_xor(mx, 16, 64));
            mx = fmaxf(mx, __shfl_xor(mx, 32, 64));
            bool upd = __any(mx > mst[qt]);
            float mnew = fmaxf(mst[qt], mx);
            float al = __builtin_amdgcn_exp2f(mst[qt] - mnew);
            mst[qt] = mnew;
            float rs = 0.f;
            for (int kt = 0; kt < 4; ++kt) {
                float p0 = __builtin_amdgcn_exp2f(st[qt][kt][0] - mnew);
                float p1 = __builtin_amdgcn_exp2f(st[qt][kt][1] - mnew);
                float p2 = __builtin_amdgcn_exp2f(st[qt][kt][2] - mnew);
                float p3 = __builtin_amdgcn_exp2f(st[qt][kt][3] - mnew);
                rs += (p0 + p1) + (p2 + p3);
                P2 pk;
                pk.w[0] = pk_bf16(p0, p1);
                pk.w[1] = pk_bf16(p2, p3);
                pb[qt][kt] = pk.v;
            }
            lst[qt] = lst[qt] * al + rs;
            if (upd) {
                for (int dt = 0; dt < 4; ++dt)
                    for (int r = 0; r < 4; ++r) accO[qt][dt][r] *= al;
            }
        }

        // O^T += V^T @ P^T : A = V^T rows (b64 LDS), B = pb (regs)
        for (int kk = 0; kk < 4; ++kk)
            for (int dt = 0; dt < 4; ++dt) {
                s16x4 vf = *(const s16x4*)(Vc + (dt * 16 + l16) * LDK + kk * 16 + quad * 4);
                for (int qt = 0; qt < 2; ++qt)
                    accO[qt][dt] = mfma16(vf, pb[qt][kk], accO[qt][dt]);
            }

        // write prefetched chunk into the other buffer (no one reads it now)
        if (pf) {
            unsigned short* Kn = Ks + (cur ^ 1) * KBUF;
            unsigned short* Vn = Vs + (cur ^ 1) * KBUF;
            *(s16x8*)(Kn + srow  * LDK + sc8) = kreg0;
            *(s16x8*)(Kn + srow1 * LDK + sc8) = kreg1;
            *(s16x8*)(Vn + srow  * LDK + sc8) = vreg0;
            *(s16x8*)(Vn + srow1 * LDK + sc8) = vreg1;
        }
        cur ^= 1;
    }

    // epilogue: reduce per-lane l across quads, then store O^T
    for (int qt = 0; qt < 2; ++qt) {
        float l = lst[qt];
        l += __shfl_xor(l, 16, 64);
        l += __shfl_xor(l, 32, 64);
        float inv = 1.f / l;
        int t = q0 + qt * 16 + l16;
        for (int dt = 0; dt < 4; ++dt) {
            U4 o;
            o.w[0] = pk_bf16(accO[qt][dt][0] * inv, accO[qt][dt][1] * inv);
            o.w[1] = pk_bf16(accO[qt][dt][2] * inv, accO[qt][dt][3] * inv);
            *(u16x4*)(Ob + ((size_t)b * T_ + t) * D_ + h * 64 + dt * 16 + quad * 4) = o.v;
        }
    }
}

// ---------------------------------------------------------------------------
extern "C" void kernel_launch(void* const* d_in, const int* in_sizes, int n_in,
                              void* d_out, int out_size, void* d_ws, size_t ws_size,
                              hipStream_t stream) {
    const float* x  = (const float*)d_in[0];
    const float* Wq = (const float*)d_in[1];
    const float* bq = (const float*)d_in[2];
    const float* Wk = (const float*)d_in[3];
    const float* bk = (const float*)d_in[4];
    const float* Wv = (const float*)d_in[5];
    const float* bv = (const float*)d_in[6];
    const float* Wo = (const float*)d_in[7];
    const float* bo = (const float*)d_in[8];
    float* out = (float*)d_out;

    // workspace: xb/Ob(16M) | Qb | Kb | Vbt (16M each) | Wcat (8M) = 72MB
    const size_t SZ = (size_t)M_ * D_ * sizeof(unsigned short);
    unsigned short* xb   = (unsigned short*)d_ws;
    unsigned short* Qb   = (unsigned short*)((char*)d_ws + 1 * SZ);
    unsigned short* Kb   = (unsigned short*)((char*)d_ws + 2 * SZ);
    unsigned short* Vbt  = (unsigned short*)((char*)d_ws + 3 * SZ);
    unsigned short* Wcat = (unsigned short*)((char*)d_ws + 4 * SZ);
    unsigned short* Ob   = xb;  // xb dead after QKV GEMM

    const float qscale = 1.4426950408889634f / 8.0f;  // log2(e)/sqrt(HD)

    dim3 blk(256);
    cvt_all<<<dim3(12288), blk, 0, stream>>>(x, Wq, Wk, Wv, Wo, xb, Wcat);
    gemm_qkv<<<dim3(M_ / 128, 24), blk, 0, stream>>>(xb, Wcat, bq, bk, bv, Qb, Kb, Vbt, qscale);
    attn<<<dim3(T_ / 128, B_ * H_), blk, 0, stream>>>(Qb, Kb, Vbt, Ob);
    gemm_o<<<dim3(M_ / 128, D_ / 128), blk, 0, stream>>>(Ob, Wcat + 3 * 1048576, bo, out);
}